// Round 4
// baseline (580.342 us; speedup 1.0000x reference)
//
#include <hip/hip_runtime.h>
#include <math.h>

#define D 128
#define KTGT 16

// ---------------------------------------------------------------------------
// K1: Wqk[d][c] = sum_j Wq[j][d] * Wk[j][c]   (i.e. Wq^T @ Wk)
//     WvT[d][c] = Wv[c][d]
// Exact reformulation: scores = tgt . (src @ Wqk),  out = ctx @ Wv^T.
// ---------------------------------------------------------------------------
__global__ void prep_kernel(const float* __restrict__ Wq,
                            const float* __restrict__ Wk,
                            const float* __restrict__ Wv,
                            float* __restrict__ Wqk,
                            float* __restrict__ WvT) {
    const int drow = blockIdx.x;   // 0..127
    const int c    = threadIdx.x;  // 0..127
    float acc = 0.0f;
    #pragma unroll 8
    for (int j = 0; j < D; ++j)
        acc = fmaf(Wq[j * D + drow], Wk[j * D + c], acc);
    Wqk[drow * D + c] = acc;
    WvT[drow * D + c] = Wv[c * D + drow];
}

// ---------------------------------------------------------------------------
// Fused kernel: per row r (block-cooperative, 8 waves = 512 threads):
//   S[c]   = sum_d src[r][d] * Wqk[d][c]          (weights in registers)
//   p[k]   = (tgt[r][k][:] . S) * 1/sqrt(128)
//   attn   = softmax_k(p)
//   ctx[d] = sum_k attn[k] * tgt[r][k][d]
//   out[c] = sum_d ctx[d] * WvT[d][c]             (weights in registers)
//
// Lane decomposition (tid = w*64 + lane, lane = h*32 + q):
//   weights: col = w*16 + (lane&15), d-slice g = (lane>>4)&3 -> [g*32, g*32+32)
//   scores:  k = 2w + h, d-chunk q (float4)
// ---------------------------------------------------------------------------
__global__ __launch_bounds__(512, 2) void fused_kernel(
        const float* __restrict__ src, const float* __restrict__ tgt,
        const float* __restrict__ Wqk, const float* __restrict__ WvT,
        float* __restrict__ out, int nrows) {
    __shared__ __align__(16) float SrcS[D];        // staged src row
    __shared__ __align__(16) float Sbuf[D];        // S row
    __shared__ __align__(16) float Scs[KTGT];      // 16 scaled scores
    __shared__ __align__(16) float CtxP[8][D];     // per-wave ctx partials
    __shared__ __align__(16) float Ctx[D];         // reduced ctx

    const int tid  = threadIdx.x;
    const int w    = tid >> 6;
    const int lane = tid & 63;
    const int h    = lane >> 5;
    const int q    = lane & 31;
    const int cl   = lane & 15;
    const int g    = (lane >> 4) & 3;
    const int col  = w * 16 + cl;
    const int myk  = 2 * w + h;
    const float scale = 0.088388347648318447f;  // 1/sqrt(128)

    // register-resident weight slices (32 + 32 VGPRs)
    float Wq_r[32], Wv_r[32];
    #pragma unroll
    for (int j = 0; j < 32; ++j) {
        Wq_r[j] = Wqk[(size_t)(g * 32 + j) * D + col];
        Wv_r[j] = WvT[(size_t)(g * 32 + j) * D + col];
    }

    const int rpb = (nrows + gridDim.x - 1) / gridDim.x;
    const int r0  = blockIdx.x * rpb;

    // prologue: stage src row r0, load tv for row r0
    if (r0 < nrows) {
        if (tid < 32)
            ((float4*)SrcS)[tid] = ((const float4*)(src + (size_t)r0 * D))[tid];
    }
    float4 tv = make_float4(0.f, 0.f, 0.f, 0.f);
    if (r0 < nrows)
        tv = ((const float4*)(tgt + (size_t)r0 * (KTGT * D)))[myk * 32 + q];
    __syncthreads();

    for (int i = 0; i < rpb; ++i) {
        const int r = r0 + i;
        if (r >= nrows) break;   // uniform across block

        // ---- step 1: S-matvec (reads SrcS staged for this row) ----
        float sS = 0.f;
        #pragma unroll
        for (int jb = 0; jb < 8; ++jb) {
            float4 s4 = *(const float4*)&SrcS[g * 32 + jb * 4];
            sS = fmaf(s4.x, Wq_r[jb * 4 + 0], sS);
            sS = fmaf(s4.y, Wq_r[jb * 4 + 1], sS);
            sS = fmaf(s4.z, Wq_r[jb * 4 + 2], sS);
            sS = fmaf(s4.w, Wq_r[jb * 4 + 3], sS);
        }
        sS += __shfl_xor(sS, 16, 64);
        sS += __shfl_xor(sS, 32, 64);
        if ((lane >> 4) == 0) Sbuf[col] = sS;
        __syncthreads();                            // A: Sbuf ready

        // ---- step 2: scores + next-row prefetch ----
        float4 Sv = *(const float4*)&Sbuf[q * 4];
        float p = tv.x * Sv.x + tv.y * Sv.y + tv.z * Sv.z + tv.w * Sv.w;
        p += __shfl_xor(p, 1, 64);
        p += __shfl_xor(p, 2, 64);
        p += __shfl_xor(p, 4, 64);
        p += __shfl_xor(p, 8, 64);
        p += __shfl_xor(p, 16, 64);
        const float myp = p * scale;                // my k's score, kept in reg
        if (q == 0) Scs[myk] = myp;

        // prefetch next row's tv + stage next src (readers are >=2 barriers away)
        const bool more = (i + 1 < rpb) && (r + 1 < nrows);
        const int rn = more ? (r + 1) : r;
        float4 tvn = ((const float4*)(tgt + (size_t)rn * (KTGT * D)))[myk * 32 + q];
        if (more && w == 1 && lane < 32)
            ((float4*)SrcS)[lane] = ((const float4*)(src + (size_t)(r + 1) * D))[lane];
        __syncthreads();                            // B: Scs ready

        // ---- step 3: softmax (redundant per lane; no dynamic indexing) ----
        float4 sc0 = *(const float4*)&Scs[0];
        float4 sc1 = *(const float4*)&Scs[4];
        float4 sc2 = *(const float4*)&Scs[8];
        float4 sc3 = *(const float4*)&Scs[12];
        float mx = fmaxf(fmaxf(fmaxf(sc0.x, sc0.y), fmaxf(sc0.z, sc0.w)),
                         fmaxf(fmaxf(fmaxf(sc1.x, sc1.y), fmaxf(sc1.z, sc1.w)),
                               fmaxf(fmaxf(fmaxf(sc2.x, sc2.y), fmaxf(sc2.z, sc2.w)),
                                     fmaxf(fmaxf(sc3.x, sc3.y), fmaxf(sc3.z, sc3.w)))));
        float sum =
            __expf(sc0.x - mx) + __expf(sc0.y - mx) + __expf(sc0.z - mx) + __expf(sc0.w - mx) +
            __expf(sc1.x - mx) + __expf(sc1.y - mx) + __expf(sc1.z - mx) + __expf(sc1.w - mx) +
            __expf(sc2.x - mx) + __expf(sc2.y - mx) + __expf(sc2.z - mx) + __expf(sc2.w - mx) +
            __expf(sc3.x - mx) + __expf(sc3.y - mx) + __expf(sc3.z - mx) + __expf(sc3.w - mx);
        const float a = __expf(myp - mx) / sum;

        // ---- step 4: ctx partial (my k, chunk q) ----
        float cx = a * tv.x, cy = a * tv.y, cz = a * tv.z, cw = a * tv.w;
        cx += __shfl_xor(cx, 32, 64);
        cy += __shfl_xor(cy, 32, 64);
        cz += __shfl_xor(cz, 32, 64);
        cw += __shfl_xor(cw, 32, 64);
        if (h == 0) *((float4*)&CtxP[w][q * 4]) = make_float4(cx, cy, cz, cw);
        __syncthreads();                            // C: CtxP ready

        // ---- step 5: reduce ctx partials (one wave) ----
        if (tid < 32) {
            float4 t0 = *(const float4*)&CtxP[0][tid * 4];
            float4 t1 = *(const float4*)&CtxP[1][tid * 4];
            float4 t2 = *(const float4*)&CtxP[2][tid * 4];
            float4 t3 = *(const float4*)&CtxP[3][tid * 4];
            float4 t4 = *(const float4*)&CtxP[4][tid * 4];
            float4 t5 = *(const float4*)&CtxP[5][tid * 4];
            float4 t6 = *(const float4*)&CtxP[6][tid * 4];
            float4 t7 = *(const float4*)&CtxP[7][tid * 4];
            float4 tt;
            tt.x = ((t0.x + t1.x) + (t2.x + t3.x)) + ((t4.x + t5.x) + (t6.x + t7.x));
            tt.y = ((t0.y + t1.y) + (t2.y + t3.y)) + ((t4.y + t5.y) + (t6.y + t7.y));
            tt.z = ((t0.z + t1.z) + (t2.z + t3.z)) + ((t4.z + t5.z) + (t6.z + t7.z));
            tt.w = ((t0.w + t1.w) + (t2.w + t3.w)) + ((t4.w + t5.w) + (t6.w + t7.w));
            *((float4*)&Ctx[tid * 4]) = tt;
        }
        __syncthreads();                            // D: Ctx ready

        // ---- step 6: out-matvec from register weights ----
        float sO = 0.f;
        #pragma unroll
        for (int jb = 0; jb < 8; ++jb) {
            float4 c4 = *(const float4*)&Ctx[g * 32 + jb * 4];
            sO = fmaf(c4.x, Wv_r[jb * 4 + 0], sO);
            sO = fmaf(c4.y, Wv_r[jb * 4 + 1], sO);
            sO = fmaf(c4.z, Wv_r[jb * 4 + 2], sO);
            sO = fmaf(c4.w, Wv_r[jb * 4 + 3], sO);
        }
        sO += __shfl_xor(sO, 16, 64);
        sO += __shfl_xor(sO, 32, 64);
        if ((lane >> 4) == 0) out[(size_t)r * D + col] = sO;

        tv = tvn;
        // no extra barrier needed: next row's Sbuf/SrcS writers are >=2
        // barriers past this row's last readers of those buffers
    }
}

extern "C" void kernel_launch(void* const* d_in, const int* in_sizes, int n_in,
                              void* d_out, int out_size, void* d_ws, size_t ws_size,
                              hipStream_t stream) {
    const float* src = (const float*)d_in[0];
    const float* tgt = (const float*)d_in[1];
    const float* Wq  = (const float*)d_in[2];
    const float* Wk  = (const float*)d_in[3];
    const float* Wv  = (const float*)d_in[4];
    float* out = (float*)d_out;

    float* Wqk = (float*)d_ws;          // 128*128 f32 = 64 KB
    float* WvT = Wqk + D * D;           // 128*128 f32 = 64 KB

    const int nrows = in_sizes[0] / D;  // b*n = 32768

    prep_kernel<<<D, D, 0, stream>>>(Wq, Wk, Wv, Wqk, WvT);
    fused_kernel<<<256, 512, 0, stream>>>(src, tgt, Wqk, WvT, out, nrows);
}

// Round 7
// 473.048 us; speedup vs baseline: 1.2268x; 1.2268x over previous
//
#include <hip/hip_runtime.h>
#include <math.h>

#define D 128
#define KTGT 16

// ---------------------------------------------------------------------------
// K1: Wqk[d][c] = sum_j Wq[j][d] * Wk[j][c]   (i.e. Wq^T @ Wk)
//     WvT[d][c] = Wv[c][d]
// Exact reformulation: scores = tgt . (src @ Wqk),  out = ctx @ Wv^T.
// ---------------------------------------------------------------------------
__global__ void prep_kernel(const float* __restrict__ Wq,
                            const float* __restrict__ Wk,
                            const float* __restrict__ Wv,
                            float* __restrict__ Wqk,
                            float* __restrict__ WvT) {
    const int drow = blockIdx.x;   // 0..127
    const int c    = threadIdx.x;  // 0..127
    float acc = 0.0f;
    #pragma unroll 8
    for (int j = 0; j < D; ++j)
        acc = fmaf(Wq[j * D + drow], Wk[j * D + c], acc);
    Wqk[drow * D + c] = acc;
    WvT[drow * D + c] = Wv[c * D + drow];
}

// ---------------------------------------------------------------------------
// Fused kernel: per row r (block-cooperative, 8 waves = 512 threads):
//   S[c]   = sum_d src[r][d] * Wqk[d][c]          (weights in registers)
//   p[k]   = (tgt[r][k][:] . S) * 1/sqrt(128)
//   attn   = softmax_k(p)
//   ctx[d] = sum_k attn[k] * tgt[r][k][d]
//   out[c] = sum_d ctx[d] * WvT[d][c]             (weights in registers)
//
// Lane decomposition (tid = w*64 + lane, lane = h*32 + q):
//   weights: col = w*16 + (lane&15), d-slice g = (lane>>4)&3 -> [g*32, g*32+32)
//   scores:  k = 2w + h, d-chunk q (float4)
//
// grid = 1024 (4 blocks/CU = 32 waves/CU): independent blocks overlap each
// other's barrier+load stalls. (grid=256 = 1 block/CU measured 306us,
// Occupancy 23%, VALUBusy 32% -- latency-serialized.)
// ---------------------------------------------------------------------------
__global__ __launch_bounds__(512, 2) void fused_kernel(
        const float* __restrict__ src, const float* __restrict__ tgt,
        const float* __restrict__ Wqk, const float* __restrict__ WvT,
        float* __restrict__ out, int nrows) {
    __shared__ __align__(16) float SrcS[D];        // staged src row
    __shared__ __align__(16) float Sbuf[D];        // S row
    __shared__ __align__(16) float Scs[KTGT];      // 16 scaled scores
    __shared__ __align__(16) float CtxP[8][D];     // per-wave ctx partials
    __shared__ __align__(16) float Ctx[D];         // reduced ctx

    const int tid  = threadIdx.x;
    const int w    = tid >> 6;
    const int lane = tid & 63;
    const int h    = lane >> 5;
    const int q    = lane & 31;
    const int cl   = lane & 15;
    const int g    = (lane >> 4) & 3;
    const int col  = w * 16 + cl;
    const int myk  = 2 * w + h;
    const float scale = 0.088388347648318447f;  // 1/sqrt(128)

    // register-resident weight slices (32 + 32 VGPRs)
    float Wq_r[32], Wv_r[32];
    #pragma unroll
    for (int j = 0; j < 32; ++j) {
        Wq_r[j] = Wqk[(size_t)(g * 32 + j) * D + col];
        Wv_r[j] = WvT[(size_t)(g * 32 + j) * D + col];
    }

    const int rpb = (nrows + gridDim.x - 1) / gridDim.x;
    const int r0  = blockIdx.x * rpb;

    // prologue: stage src row r0, load tv for row r0
    if (r0 < nrows) {
        if (tid < 32)
            ((float4*)SrcS)[tid] = ((const float4*)(src + (size_t)r0 * D))[tid];
    }
    float4 tv = make_float4(0.f, 0.f, 0.f, 0.f);
    if (r0 < nrows)
        tv = ((const float4*)(tgt + (size_t)r0 * (KTGT * D)))[myk * 32 + q];
    __syncthreads();

    for (int i = 0; i < rpb; ++i) {
        const int r = r0 + i;
        if (r >= nrows) break;   // uniform across block

        // ---- step 1: S-matvec (reads SrcS staged for this row) ----
        float sS = 0.f;
        #pragma unroll
        for (int jb = 0; jb < 8; ++jb) {
            float4 s4 = *(const float4*)&SrcS[g * 32 + jb * 4];
            sS = fmaf(s4.x, Wq_r[jb * 4 + 0], sS);
            sS = fmaf(s4.y, Wq_r[jb * 4 + 1], sS);
            sS = fmaf(s4.z, Wq_r[jb * 4 + 2], sS);
            sS = fmaf(s4.w, Wq_r[jb * 4 + 3], sS);
        }
        sS += __shfl_xor(sS, 16, 64);
        sS += __shfl_xor(sS, 32, 64);
        if ((lane >> 4) == 0) Sbuf[col] = sS;
        __syncthreads();                            // A: Sbuf ready

        // ---- step 2: scores + next-row prefetch ----
        float4 Sv = *(const float4*)&Sbuf[q * 4];
        float p = tv.x * Sv.x + tv.y * Sv.y + tv.z * Sv.z + tv.w * Sv.w;
        p += __shfl_xor(p, 1, 64);
        p += __shfl_xor(p, 2, 64);
        p += __shfl_xor(p, 4, 64);
        p += __shfl_xor(p, 8, 64);
        p += __shfl_xor(p, 16, 64);
        const float myp = p * scale;                // my k's score, kept in reg
        if (q == 0) Scs[myk] = myp;

        // prefetch next row's tv + stage next src (readers are >=2 barriers away)
        const bool more = (i + 1 < rpb) && (r + 1 < nrows);
        const int rn = more ? (r + 1) : r;
        float4 tvn = ((const float4*)(tgt + (size_t)rn * (KTGT * D)))[myk * 32 + q];
        if (more && w == 1 && lane < 32)
            ((float4*)SrcS)[lane] = ((const float4*)(src + (size_t)(r + 1) * D))[lane];
        __syncthreads();                            // B: Scs ready

        // ---- step 3: softmax (redundant per lane; no dynamic indexing) ----
        float4 sc0 = *(const float4*)&Scs[0];
        float4 sc1 = *(const float4*)&Scs[4];
        float4 sc2 = *(const float4*)&Scs[8];
        float4 sc3 = *(const float4*)&Scs[12];
        float mx = fmaxf(fmaxf(fmaxf(sc0.x, sc0.y), fmaxf(sc0.z, sc0.w)),
                         fmaxf(fmaxf(fmaxf(sc1.x, sc1.y), fmaxf(sc1.z, sc1.w)),
                               fmaxf(fmaxf(fmaxf(sc2.x, sc2.y), fmaxf(sc2.z, sc2.w)),
                                     fmaxf(fmaxf(sc3.x, sc3.y), fmaxf(sc3.z, sc3.w)))));
        float sum =
            __expf(sc0.x - mx) + __expf(sc0.y - mx) + __expf(sc0.z - mx) + __expf(sc0.w - mx) +
            __expf(sc1.x - mx) + __expf(sc1.y - mx) + __expf(sc1.z - mx) + __expf(sc1.w - mx) +
            __expf(sc2.x - mx) + __expf(sc2.y - mx) + __expf(sc2.z - mx) + __expf(sc2.w - mx) +
            __expf(sc3.x - mx) + __expf(sc3.y - mx) + __expf(sc3.z - mx) + __expf(sc3.w - mx);
        const float a = __expf(myp - mx) / sum;

        // ---- step 4: ctx partial (my k, chunk q) ----
        float cx = a * tv.x, cy = a * tv.y, cz = a * tv.z, cw = a * tv.w;
        cx += __shfl_xor(cx, 32, 64);
        cy += __shfl_xor(cy, 32, 64);
        cz += __shfl_xor(cz, 32, 64);
        cw += __shfl_xor(cw, 32, 64);
        if (h == 0) *((float4*)&CtxP[w][q * 4]) = make_float4(cx, cy, cz, cw);
        __syncthreads();                            // C: CtxP ready

        // ---- step 5: reduce ctx partials (one wave) ----
        if (tid < 32) {
            float4 t0 = *(const float4*)&CtxP[0][tid * 4];
            float4 t1 = *(const float4*)&CtxP[1][tid * 4];
            float4 t2 = *(const float4*)&CtxP[2][tid * 4];
            float4 t3 = *(const float4*)&CtxP[3][tid * 4];
            float4 t4 = *(const float4*)&CtxP[4][tid * 4];
            float4 t5 = *(const float4*)&CtxP[5][tid * 4];
            float4 t6 = *(const float4*)&CtxP[6][tid * 4];
            float4 t7 = *(const float4*)&CtxP[7][tid * 4];
            float4 tt;
            tt.x = ((t0.x + t1.x) + (t2.x + t3.x)) + ((t4.x + t5.x) + (t6.x + t7.x));
            tt.y = ((t0.y + t1.y) + (t2.y + t3.y)) + ((t4.y + t5.y) + (t6.y + t7.y));
            tt.z = ((t0.z + t1.z) + (t2.z + t3.z)) + ((t4.z + t5.z) + (t6.z + t7.z));
            tt.w = ((t0.w + t1.w) + (t2.w + t3.w)) + ((t4.w + t5.w) + (t6.w + t7.w));
            *((float4*)&Ctx[tid * 4]) = tt;
        }
        __syncthreads();                            // D: Ctx ready

        // ---- step 6: out-matvec from register weights ----
        float sO = 0.f;
        #pragma unroll
        for (int jb = 0; jb < 8; ++jb) {
            float4 c4 = *(const float4*)&Ctx[g * 32 + jb * 4];
            sO = fmaf(c4.x, Wv_r[jb * 4 + 0], sO);
            sO = fmaf(c4.y, Wv_r[jb * 4 + 1], sO);
            sO = fmaf(c4.z, Wv_r[jb * 4 + 2], sO);
            sO = fmaf(c4.w, Wv_r[jb * 4 + 3], sO);
        }
        sO += __shfl_xor(sO, 16, 64);
        sO += __shfl_xor(sO, 32, 64);
        if ((lane >> 4) == 0) out[(size_t)r * D + col] = sO;

        tv = tvn;
        // no extra barrier needed: next row's Sbuf/SrcS writers are >=2
        // barriers past this row's last readers of those buffers
    }
}

extern "C" void kernel_launch(void* const* d_in, const int* in_sizes, int n_in,
                              void* d_out, int out_size, void* d_ws, size_t ws_size,
                              hipStream_t stream) {
    const float* src = (const float*)d_in[0];
    const float* tgt = (const float*)d_in[1];
    const float* Wq  = (const float*)d_in[2];
    const float* Wk  = (const float*)d_in[3];
    const float* Wv  = (const float*)d_in[4];
    float* out = (float*)d_out;

    float* Wqk = (float*)d_ws;          // 128*128 f32 = 64 KB
    float* WvT = Wqk + D * D;           // 128*128 f32 = 64 KB

    const int nrows = in_sizes[0] / D;  // b*n = 32768

    prep_kernel<<<D, D, 0, stream>>>(Wq, Wk, Wv, Wqk, WvT);
    // 1024 blocks = 4 blocks/CU (2048 thr/CU = 100% occupancy), 32 rows/block
    fused_kernel<<<1024, 512, 0, stream>>>(src, tgt, Wqk, WvT, out, nrows);
}

// Round 8
// 434.239 us; speedup vs baseline: 1.3365x; 1.0894x over previous
//
#include <hip/hip_runtime.h>
#include <math.h>

#define D 128
#define KTGT 16

// ---------------------------------------------------------------------------
// Split pipeline (empirically faster than the fused block-cooperative kernel:
// fused = 201us @ Occupancy 43 / VALUBusy 50 -- per-row barrier+shuffle
// critical path dominates. Split attn is wave-independent streaming.)
//   K1 prep:    Wqk = Wq^T@Wk, WvT = Wv^T
//   K2 rowgemm: S = src @ Wqk          -> d_out
//   K3 attn:    scores/softmax/ctx     in-place on d_out
//   K4 rowgemm: out = ctx @ WvT        in-place on d_out
// ---------------------------------------------------------------------------
__global__ void prep_kernel(const float* __restrict__ Wq,
                            const float* __restrict__ Wk,
                            const float* __restrict__ Wv,
                            float* __restrict__ Wqk,
                            float* __restrict__ WvT) {
    const int drow = blockIdx.x;   // 0..127
    const int c    = threadIdx.x;  // 0..127
    float acc = 0.0f;
    #pragma unroll 8
    for (int j = 0; j < D; ++j)
        acc = fmaf(Wq[j * D + drow], Wk[j * D + c], acc);
    Wqk[drow * D + c] = acc;
    WvT[drow * D + c] = Wv[c * D + drow];
}

// ---------------------------------------------------------------------------
// K2/K4: C[r][c] = sum_d A[r][d] * B[d][c] for 32 rows per block.
// 256 threads: thread = (rblk = tid>>5 -> 4 rows, cblk = tid&31 -> 4 cols),
// A tile staged in LDS (reads are broadcast), B read from L2 as float4.
// Safe in-place (C == A): stage-then-sync; block only writes its own rows.
// ---------------------------------------------------------------------------
__global__ __launch_bounds__(256) void rowgemm_kernel(const float* __restrict__ A,
                                                      const float* __restrict__ B,
                                                      float* __restrict__ C) {
    __shared__ float Alds[32][D];
    const int r0 = blockIdx.x * 32;
    {
        const float4* Ag = reinterpret_cast<const float4*>(A + (size_t)r0 * D);
        float4* Al = reinterpret_cast<float4*>(&Alds[0][0]);
        #pragma unroll
        for (int i = 0; i < 4; ++i)
            Al[threadIdx.x + i * 256] = Ag[threadIdx.x + i * 256];
    }
    __syncthreads();

    const int cblk = threadIdx.x & 31;  // cols cblk*4 .. +3
    const int rblk = threadIdx.x >> 5;  // rows rblk*4 .. +3
    float acc[4][4] = {};
    const float4* B4 = reinterpret_cast<const float4*>(B);

    for (int d0 = 0; d0 < D; d0 += 4) {
        float4 a[4];
        #pragma unroll
        for (int j = 0; j < 4; ++j)
            a[j] = *reinterpret_cast<const float4*>(&Alds[rblk * 4 + j][d0]);
        #pragma unroll
        for (int dd = 0; dd < 4; ++dd) {
            float4 w = B4[(d0 + dd) * 32 + cblk];
            #pragma unroll
            for (int j = 0; j < 4; ++j) {
                float aj = (&a[j].x)[dd];
                acc[j][0] = fmaf(aj, w.x, acc[j][0]);
                acc[j][1] = fmaf(aj, w.y, acc[j][1]);
                acc[j][2] = fmaf(aj, w.z, acc[j][2]);
                acc[j][3] = fmaf(aj, w.w, acc[j][3]);
            }
        }
    }

    #pragma unroll
    for (int j = 0; j < 4; ++j) {
        float4 o = make_float4(acc[j][0], acc[j][1], acc[j][2], acc[j][3]);
        *reinterpret_cast<float4*>(C + (size_t)(r0 + rblk * 4 + j) * D + cblk * 4) = o;
    }
}

// ---------------------------------------------------------------------------
// K3: per (b,n) row r (one wave each, grid-stride, no block barriers):
//   scores[k] = (tgt[r,k,:] . S[r,:]) * 1/sqrt(128), softmax over k=16,
//   ctx[r,:]  = sum_k attn[k] * tgt[r,k,:]        (written in-place over S)
// Lane l owns float4 d-chunk d4=l&31; half h=l>>5 owns k = 2i+h, i=0..7.
// grid 2048x256 = 8192 waves = 8 blocks/CU -> 32 waves/CU (full occupancy).
// ---------------------------------------------------------------------------
__global__ __launch_bounds__(256) void attn_kernel(const float* __restrict__ tgt,
                                                   float* __restrict__ SC,
                                                   int nrows) {
    const int lane = threadIdx.x & 63;
    const int wid  = (int)((blockIdx.x * blockDim.x + threadIdx.x) >> 6);
    const int nw   = (int)((gridDim.x * blockDim.x) >> 6);
    const int d4   = lane & 31;
    const float scale = 0.088388347648318447f;  // 1/sqrt(128)

    for (int r = wid; r < nrows; r += nw) {
        float4 Sv = *reinterpret_cast<const float4*>(SC + (size_t)r * D + d4 * 4);
        const float4* T4 = reinterpret_cast<const float4*>(tgt + (size_t)r * KTGT * D);

        float4 tv[8];
        float p[8];
        #pragma unroll
        for (int i = 0; i < 8; ++i) {
            tv[i] = T4[i * 64 + lane];  // k = 2i + (lane>>5), chunk d4
            p[i] = tv[i].x * Sv.x + tv[i].y * Sv.y + tv[i].z * Sv.z + tv[i].w * Sv.w;
        }
        // reduce over the 32 d-chunks (within each 32-lane half)
        #pragma unroll
        for (int m = 1; m <= 16; m <<= 1) {
            #pragma unroll
            for (int i = 0; i < 8; ++i)
                p[i] += __shfl_xor(p[i], m, 64);
        }
        float q[8];
        #pragma unroll
        for (int i = 0; i < 8; ++i) {
            p[i] *= scale;                   // score for k = 2i + half
            q[i] = __shfl_xor(p[i], 32, 64); // score for k = 2i + (1-half)
        }
        float mx = -1e30f;
        #pragma unroll
        for (int i = 0; i < 8; ++i) mx = fmaxf(mx, fmaxf(p[i], q[i]));
        float sum = 0.0f;
        float ep[8];
        #pragma unroll
        for (int i = 0; i < 8; ++i) {
            ep[i] = __expf(p[i] - mx);
            float eq = __expf(q[i] - mx);
            sum += ep[i] + eq;
        }
        const float inv = 1.0f / sum;
        float cx = 0.f, cy = 0.f, cz = 0.f, cw = 0.f;
        #pragma unroll
        for (int i = 0; i < 8; ++i) {
            float w = ep[i] * inv;
            cx = fmaf(w, tv[i].x, cx);
            cy = fmaf(w, tv[i].y, cy);
            cz = fmaf(w, tv[i].z, cz);
            cw = fmaf(w, tv[i].w, cw);
        }
        // add the partner half's 8 k's (same d-chunk, complementary k set)
        cx += __shfl_xor(cx, 32, 64);
        cy += __shfl_xor(cy, 32, 64);
        cz += __shfl_xor(cz, 32, 64);
        cw += __shfl_xor(cw, 32, 64);
        if (lane < 32) {
            float4 o = make_float4(cx, cy, cz, cw);
            *reinterpret_cast<float4*>(SC + (size_t)r * D + d4 * 4) = o;
        }
    }
}

extern "C" void kernel_launch(void* const* d_in, const int* in_sizes, int n_in,
                              void* d_out, int out_size, void* d_ws, size_t ws_size,
                              hipStream_t stream) {
    const float* src = (const float*)d_in[0];
    const float* tgt = (const float*)d_in[1];
    const float* Wq  = (const float*)d_in[2];
    const float* Wk  = (const float*)d_in[3];
    const float* Wv  = (const float*)d_in[4];
    float* out = (float*)d_out;

    float* Wqk = (float*)d_ws;          // 128*128 f32 = 64 KB
    float* WvT = Wqk + D * D;           // 128*128 f32 = 64 KB

    const int nrows = in_sizes[0] / D;  // b*n = 32768

    prep_kernel<<<D, D, 0, stream>>>(Wq, Wk, Wv, Wqk, WvT);
    rowgemm_kernel<<<nrows / 32, 256, 0, stream>>>(src, Wqk, out);
    attn_kernel<<<2048, 256, 0, stream>>>(tgt, out, nrows);
    rowgemm_kernel<<<nrows / 32, 256, 0, stream>>>(out, WvT, out);
}

// Round 9
// 434.130 us; speedup vs baseline: 1.3368x; 1.0003x over previous
//
#include <hip/hip_runtime.h>
#include <math.h>

#define D 128
#define KTGT 16

// ---------------------------------------------------------------------------
// Split pipeline (empirically faster than fused block-cooperative: fused =
// 201us @ Occ 43 / VALUBusy 50; split kernels total ~170us).
//   K1 prep:    Wqk = Wq^T@Wk, WvT = Wv^T
//   K2 rowgemm: S = src @ Wqk          -> d_out
//   K3 attn:    scores/softmax/ctx     in-place on d_out (row-ahead pipelined)
//   K4 rowgemm: out = ctx @ WvT        in-place on d_out
// ---------------------------------------------------------------------------
__global__ void prep_kernel(const float* __restrict__ Wq,
                            const float* __restrict__ Wk,
                            const float* __restrict__ Wv,
                            float* __restrict__ Wqk,
                            float* __restrict__ WvT) {
    const int drow = blockIdx.x;   // 0..127
    const int c    = threadIdx.x;  // 0..127
    float acc = 0.0f;
    #pragma unroll 8
    for (int j = 0; j < D; ++j)
        acc = fmaf(Wq[j * D + drow], Wk[j * D + c], acc);
    Wqk[drow * D + c] = acc;
    WvT[drow * D + c] = Wv[c * D + drow];
}

// ---------------------------------------------------------------------------
// K2/K4: C[r][c] = sum_d A[r][d] * B[d][c] for 32 rows per block.
// 256 threads: (rblk = tid>>5 -> 4 rows, cblk = tid&31 -> 4 cols),
// A tile in LDS, B from L2 as float4. Safe in-place (C == A).
// ---------------------------------------------------------------------------
__global__ __launch_bounds__(256) void rowgemm_kernel(const float* __restrict__ A,
                                                      const float* __restrict__ B,
                                                      float* __restrict__ C) {
    __shared__ float Alds[32][D];
    const int r0 = blockIdx.x * 32;
    {
        const float4* Ag = reinterpret_cast<const float4*>(A + (size_t)r0 * D);
        float4* Al = reinterpret_cast<float4*>(&Alds[0][0]);
        #pragma unroll
        for (int i = 0; i < 4; ++i)
            Al[threadIdx.x + i * 256] = Ag[threadIdx.x + i * 256];
    }
    __syncthreads();

    const int cblk = threadIdx.x & 31;  // cols cblk*4 .. +3
    const int rblk = threadIdx.x >> 5;  // rows rblk*4 .. +3
    float acc[4][4] = {};
    const float4* B4 = reinterpret_cast<const float4*>(B);

    for (int d0 = 0; d0 < D; d0 += 4) {
        float4 a[4];
        #pragma unroll
        for (int j = 0; j < 4; ++j)
            a[j] = *reinterpret_cast<const float4*>(&Alds[rblk * 4 + j][d0]);
        #pragma unroll
        for (int dd = 0; dd < 4; ++dd) {
            float4 w = B4[(d0 + dd) * 32 + cblk];
            #pragma unroll
            for (int j = 0; j < 4; ++j) {
                float aj = (&a[j].x)[dd];
                acc[j][0] = fmaf(aj, w.x, acc[j][0]);
                acc[j][1] = fmaf(aj, w.y, acc[j][1]);
                acc[j][2] = fmaf(aj, w.z, acc[j][2]);
                acc[j][3] = fmaf(aj, w.w, acc[j][3]);
            }
        }
    }

    #pragma unroll
    for (int j = 0; j < 4; ++j) {
        float4 o = make_float4(acc[j][0], acc[j][1], acc[j][2], acc[j][3]);
        *reinterpret_cast<float4*>(C + (size_t)(r0 + rblk * 4 + j) * D + cblk * 4) = o;
    }
}

// ---------------------------------------------------------------------------
// K3: one wave per row, grid-stride, ROW-AHEAD PIPELINED: issue row r+nw's
// 9 loads (8x1KB tv + Sv) before computing row r, so HBM latency hides
// under the ~700cy compute tail. (v1 was bursty: load->wait->compute with
// zero bytes in flight during compute; attn measured ~140us vs ~45us BW
// model.) VGPR ~112 -> launch_bounds(256,4): 16 waves/CU, 144KB in flight.
// Lane l owns d-chunk d4=l&31; half h=l>>5 owns k = 2i+h, i=0..7.
// ---------------------------------------------------------------------------
__global__ __launch_bounds__(256, 4) void attn_kernel(const float* __restrict__ tgt,
                                                      float* __restrict__ SC,
                                                      int nrows) {
    const int lane = threadIdx.x & 63;
    const int nw   = (int)((gridDim.x * blockDim.x) >> 6);
    const int d4   = lane & 31;
    const float scale = 0.088388347648318447f;  // 1/sqrt(128)

    int r = (int)((blockIdx.x * blockDim.x + threadIdx.x) >> 6);
    if (r >= nrows) return;

    // prologue: load row r
    float4 tv[8];
    {
        const float4* T4 = reinterpret_cast<const float4*>(tgt + (size_t)r * KTGT * D);
        #pragma unroll
        for (int i = 0; i < 8; ++i) tv[i] = T4[i * 64 + lane];
    }
    float4 Sv = *reinterpret_cast<const float4*>(SC + (size_t)r * D + d4 * 4);
    Sv.x *= scale; Sv.y *= scale; Sv.z *= scale; Sv.w *= scale;

    for (;;) {
        const int rn   = r + nw;
        const bool more = rn < nrows;
        const int rp   = more ? rn : r;

        // ---- prefetch next row (loads in flight during compute below) ----
        float4 tvn[8];
        {
            const float4* T4n = reinterpret_cast<const float4*>(tgt + (size_t)rp * KTGT * D);
            #pragma unroll
            for (int i = 0; i < 8; ++i) tvn[i] = T4n[i * 64 + lane];
        }
        float4 Svn = *reinterpret_cast<const float4*>(SC + (size_t)rp * D + d4 * 4);

        // ---- compute current row ----
        float p[8];
        #pragma unroll
        for (int i = 0; i < 8; ++i)
            p[i] = tv[i].x * Sv.x + tv[i].y * Sv.y + tv[i].z * Sv.z + tv[i].w * Sv.w;
        #pragma unroll
        for (int m = 1; m <= 16; m <<= 1) {
            #pragma unroll
            for (int i = 0; i < 8; ++i)
                p[i] += __shfl_xor(p[i], m, 64);
        }
        float q[8];
        #pragma unroll
        for (int i = 0; i < 8; ++i)
            q[i] = __shfl_xor(p[i], 32, 64);  // other half's scores
        float mx = -1e30f;
        #pragma unroll
        for (int i = 0; i < 8; ++i) mx = fmaxf(mx, fmaxf(p[i], q[i]));
        float sum = 0.0f;
        float ep[8];
        #pragma unroll
        for (int i = 0; i < 8; ++i) {
            ep[i] = __expf(p[i] - mx);
            float eq = __expf(q[i] - mx);
            sum += ep[i] + eq;
        }
        const float inv = 1.0f / sum;
        float cx = 0.f, cy = 0.f, cz = 0.f, cw = 0.f;
        #pragma unroll
        for (int i = 0; i < 8; ++i) {
            float wgt = ep[i] * inv;
            cx = fmaf(wgt, tv[i].x, cx);
            cy = fmaf(wgt, tv[i].y, cy);
            cz = fmaf(wgt, tv[i].z, cz);
            cw = fmaf(wgt, tv[i].w, cw);
        }
        cx += __shfl_xor(cx, 32, 64);
        cy += __shfl_xor(cy, 32, 64);
        cz += __shfl_xor(cz, 32, 64);
        cw += __shfl_xor(cw, 32, 64);
        if (lane < 32) {
            float4 o = make_float4(cx, cy, cz, cw);
            *reinterpret_cast<float4*>(SC + (size_t)r * D + d4 * 4) = o;
        }

        if (!more) break;
        r = rn;
        #pragma unroll
        for (int i = 0; i < 8; ++i) tv[i] = tvn[i];
        Sv.x = Svn.x * scale; Sv.y = Svn.y * scale;
        Sv.z = Svn.z * scale; Sv.w = Svn.w * scale;
    }
}

extern "C" void kernel_launch(void* const* d_in, const int* in_sizes, int n_in,
                              void* d_out, int out_size, void* d_ws, size_t ws_size,
                              hipStream_t stream) {
    const float* src = (const float*)d_in[0];
    const float* tgt = (const float*)d_in[1];
    const float* Wq  = (const float*)d_in[2];
    const float* Wk  = (const float*)d_in[3];
    const float* Wv  = (const float*)d_in[4];
    float* out = (float*)d_out;

    float* Wqk = (float*)d_ws;          // 128*128 f32 = 64 KB
    float* WvT = Wqk + D * D;           // 128*128 f32 = 64 KB

    const int nrows = in_sizes[0] / D;  // b*n = 32768

    prep_kernel<<<D, D, 0, stream>>>(Wq, Wk, Wv, Wqk, WvT);
    rowgemm_kernel<<<nrows / 32, 256, 0, stream>>>(src, Wqk, out);
    attn_kernel<<<2048, 256, 0, stream>>>(tgt, out, nrows);
    rowgemm_kernel<<<nrows / 32, 256, 0, stream>>>(out, WvT, out);
}